// Round 1
// baseline (16004.462 us; speedup 1.0000x reference)
//
#include <hip/hip_runtime.h>
#include <hip/hip_bf16.h>
#include <stdint.h>

#define T_STEPS 1024
#define NBLK    128     // recurrent blocks; each owns 4 hidden cols
#define NTHR    256

typedef __attribute__((ext_vector_type(8))) short short8;
typedef __attribute__((ext_vector_type(4))) float float4v;
typedef unsigned short ushort_t;

__device__ __forceinline__ ushort_t f2bf(float f) {
    __hip_bfloat16 h = __float2bfloat16(f);  // RNE
    return __builtin_bit_cast(ushort_t, h);
}

// ---------------------------------------------------------------------------
// Setup: WiT/WhT = bf16 transpose [2048][512]; ring slot1 = h0 (permuted);
// cnt[1024] = 0.
// work items: 1048576 (WiT) + 1048576 (WhT) + 32768 (ring) + 1024 (cnt)
// ---------------------------------------------------------------------------
__global__ void lstm_setup(const float* __restrict__ Wi,
                           const float* __restrict__ Wh,
                           const float* __restrict__ h0,
                           ushort_t* __restrict__ WiT,
                           ushort_t* __restrict__ WhT,
                           ushort_t* __restrict__ ring,
                           unsigned int* __restrict__ cnt) {
    size_t i = (size_t)blockIdx.x * NTHR + threadIdx.x;
    if (i < 1048576) {
        size_t c = i >> 9, k = i & 511;
        WiT[i] = f2bf(Wi[k * 2048 + c]);
    } else if (i < 2097152) {
        size_t j = i - 1048576;
        size_t c = j >> 9, k = j & 511;
        WhT[j] = f2bf(Wh[k * 2048 + c]);
    } else if (i < 2129920) {
        size_t j = i - 2097152;              // [blk][b][hc] flat
        size_t blk = j >> 8, b = (j >> 2) & 63, hc = j & 3;
        ring[32768 + j] = f2bf(h0[b * 512 + blk * 4 + hc]);
    } else if (i < 2130944) {
        cnt[i - 2129920] = 0u;
    }
}

// ---------------------------------------------------------------------------
// Persistent recurrent kernel. 128 blocks x 256 threads.
// Block owns hidden cols [blk*4, blk*4+4) -> z cols {g*512 + blk*4 + hc}.
// MFMA 16x16x32 bf16; A = activations (rows=batch), B = weight cols.
// A-frag: lane holds A[m=lane&15][k=(lane>>4)*8 + j]
// B-frag: lane holds B[k=(lane>>4)*8 + j][n=lane&15]
// C/D:    reg r holds D[row=(lane>>4)*4+r][col=lane&15]
// ---------------------------------------------------------------------------
__global__ __launch_bounds__(NTHR) void lstm_persist(
    const float* __restrict__ X,        // [1024][64][512] fp32
    const float* __restrict__ c0,       // [64][512]
    const float* __restrict__ bias,     // [2048]
    const ushort_t* __restrict__ WiT,   // [2048][512] bf16
    const ushort_t* __restrict__ WhT,   // [2048][512] bf16
    ushort_t* __restrict__ ring,        // [2][128*64*4] bf16
    unsigned int* __restrict__ cnt,     // [1024]
    float* __restrict__ out)            // ys | cT | hT
{
    const int blk  = blockIdx.x;
    const int tid  = threadIdx.x;
    const int lane = tid & 63;
    const int wave = tid >> 6;
    const int l15  = lane & 15;
    const int quad = lane >> 4;

    // 64 KB LDS: h stage [64 rows][512 bf16] XOR-swizzled at 16B-chunk level.
    // After h is consumed each step, bytes [0,4352) are reused as z_tile
    // [64][17] fp32 and [4352,4864) as hout [64][4] bf16 (barrier-protected).
    __shared__ alignas(16) char smem[65536];
    float*    ztile = (float*)smem;
    ushort_t* hout  = (ushort_t*)(smem + 4352);

    // --- per-lane constant fragments: weight columns in registers ---
    const int zc   = l15;                 // 0..15
    const int gate = zc >> 2;             // 0:i 1:f 2:g 3:o
    const int hc   = zc & 3;
    const int col  = gate * 512 + blk * 4 + hc;   // 0..2047

    short8 wib[16], whb[16];
    {
        const short8* wp = (const short8*)(WiT + (size_t)col * 512);
        const short8* hp = (const short8*)(WhT + (size_t)col * 512);
#pragma unroll
        for (int kk = 0; kk < 16; kk++) {
            wib[kk] = wp[kk * 4 + quad];   // k = kk*32 + quad*8 .. +7
            whb[kk] = hp[kk * 4 + quad];
        }
    }
    const float bval = bias[col];

    // gate-phase role: one (row,hc) per thread; c state in a register forever
    const int grow = tid >> 2;
    const int ghc  = tid & 3;
    float c_reg = c0[grow * 512 + blk * 4 + ghc];

    const int arow = wave * 16 + l15;     // A-fragment row (batch)

    for (int t = 0; t < T_STEPS; t++) {
        // ---- x_t @ Wi (global fp32 -> bf16 frags), overlaps sync skew ----
        float4v acc = {bval, bval, bval, bval};
        const float* xbase = X + ((size_t)t * 64 + arow) * 512;
#pragma unroll
        for (int kk = 0; kk < 16; kk++) {
            float4v x0 = *(const float4v*)(xbase + kk * 32 + quad * 8);
            float4v x1 = *(const float4v*)(xbase + kk * 32 + quad * 8 + 4);
            short8 a;
            a[0] = (short)f2bf(x0.x); a[1] = (short)f2bf(x0.y);
            a[2] = (short)f2bf(x0.z); a[3] = (short)f2bf(x0.w);
            a[4] = (short)f2bf(x1.x); a[5] = (short)f2bf(x1.y);
            a[6] = (short)f2bf(x1.z); a[7] = (short)f2bf(x1.w);
            acc = __builtin_amdgcn_mfma_f32_16x16x32_bf16(a, wib[kk], acc, 0, 0, 0);
        }

        // ---- wait for all blocks' h_{t-1} ----
        if (t > 0 && tid == 0) {
            while (__hip_atomic_load(&cnt[t - 1], __ATOMIC_ACQUIRE,
                                     __HIP_MEMORY_SCOPE_AGENT) < NBLK)
                __builtin_amdgcn_s_sleep(1);
        }
        __syncthreads();   // B1: sync-with writers; prev-step LDS reads done

        // ---- stage h_{t-1}: ring (bf16 [blk'][b][4]) -> swizzled LDS ----
        const ushort_t* rslot = ring + (size_t)((t + 1) & 1) * 32768;
#pragma unroll
        for (int i = 0; i < 16; i++) {
            int f  = i * 256 + tid;        // 16B chunk 0..4095
            uint4 v = ((const uint4*)rslot)[f];
            int bp  = f >> 5;              // source block 0..127 (k-group)
            int b0  = (f & 31) * 2;        // batch rows b0, b0+1
            int c16 = bp >> 1, half = bp & 1;
            uint2* p0 = (uint2*)(smem + b0 * 1024 +
                                 ((c16 ^ (b0 & 15)) * 16) + half * 8);
            uint2* p1 = (uint2*)(smem + (b0 + 1) * 1024 +
                                 ((c16 ^ ((b0 + 1) & 15)) * 16) + half * 8);
            uint2 w0; w0.x = v.x; w0.y = v.y;
            uint2 w1; w1.x = v.z; w1.y = v.w;
            *p0 = w0; *p1 = w1;
        }
        __syncthreads();   // B2: staging visible

        // ---- h_{t-1} @ Wh ----
#pragma unroll
        for (int kk = 0; kk < 16; kk++) {
            int chunk = kk * 4 + quad;
            int ch    = chunk ^ (arow & 15);
            short8 a  = *(const short8*)(smem + arow * 1024 + ch * 16);
            acc = __builtin_amdgcn_mfma_f32_16x16x32_bf16(a, whb[kk], acc, 0, 0, 0);
        }
        __syncthreads();   // B3: all a-frag reads done (z_tile overlays rows 0-4)

        // ---- scatter z to LDS, regroup gates per (row, hc) ----
#pragma unroll
        for (int r = 0; r < 4; r++)
            ztile[(wave * 16 + quad * 4 + r) * 17 + l15] = acc[r];
        __syncthreads();   // B4

        float zi = ztile[grow * 17 + 0  + ghc];
        float zf = ztile[grow * 17 + 4  + ghc];
        float zg = ztile[grow * 17 + 8  + ghc];
        float zo = ztile[grow * 17 + 12 + ghc];
        float si = 1.f / (1.f + __expf(-zi));
        float sf = 1.f / (1.f + __expf(-zf));
        float tg = tanhf(zg);
        float so = 1.f / (1.f + __expf(-zo));
        float nc = sf * c_reg + si * tg;
        float nh = so * tanhf(nc);
        c_reg = nc;

        out[(size_t)t * 32768 + grow * 512 + blk * 4 + ghc] = nh;
        hout[grow * 4 + ghc] = f2bf(nh);
        if (t == T_STEPS - 1) {
            out[33554432u + grow * 512 + blk * 4 + ghc] = nc;           // cT
            out[33554432u + 32768u + grow * 512 + blk * 4 + ghc] = nh;  // hT
        }
        __syncthreads();   // B5: hout visible

        if (tid < 64) {
            ushort_t* wslot = ring + (size_t)(t & 1) * 32768 + (blk * 64 + tid) * 4;
            *(uint2*)wslot = *(const uint2*)(hout + tid * 4);
        }
        __syncthreads();   // B6: ring stores drained (vmcnt(0) at barrier)

        if (tid == 0)
            __hip_atomic_fetch_add(&cnt[t], 1u, __ATOMIC_RELEASE,
                                   __HIP_MEMORY_SCOPE_AGENT);
    }
}

// ---------------------------------------------------------------------------
extern "C" void kernel_launch(void* const* d_in, const int* in_sizes, int n_in,
                              void* d_out, int out_size, void* d_ws, size_t ws_size,
                              hipStream_t stream) {
    const float* X    = (const float*)d_in[0];   // [1024][64][512]
    const float* c0   = (const float*)d_in[1];   // [64][512]
    const float* h0   = (const float*)d_in[2];   // [64][512]
    const float* Wi   = (const float*)d_in[3];   // [512][2048]
    const float* Wh   = (const float*)d_in[4];   // [512][2048]
    const float* bias = (const float*)d_in[5];   // [2048]

    char* ws = (char*)d_ws;
    ushort_t*     WiT  = (ushort_t*)ws;                    // 2,097,152 B
    ushort_t*     WhT  = (ushort_t*)(ws + 2097152);        // 2,097,152 B
    ushort_t*     ring = (ushort_t*)(ws + 4194304);        //   131,072 B
    unsigned int* cnt  = (unsigned int*)(ws + 4325376);    //     4,096 B
    // total ws need: 4,329,472 B

    lstm_setup<<<8324, NTHR, 0, stream>>>(Wi, Wh, h0, WiT, WhT, ring, cnt);
    lstm_persist<<<NBLK, NTHR, 0, stream>>>(X, c0, bias, WiT, WhT, ring, cnt,
                                            (float*)d_out);
}